// Round 7
// baseline (135.880 us; speedup 1.0000x reference)
//
#include <hip/hip_runtime.h>
#include <math.h>

#define D_MODEL 4096
#define NE 64
#define TPB 32                  // tokens per block (one 32x32 MFMA tile)
#define KPW 512                 // k's per wave (8 waves x 512 = 4096)
#define WSTEPS 32               // 512 / 16
#define WS_SHORTS (256 * 2 * 64 * 8)   // 262144 shorts per (hi|lo) region

typedef __attribute__((ext_vector_type(8))) short short8;
typedef __attribute__((ext_vector_type(16))) float f32x16;

// Split 8 fp32 -> bf16 hi (round-nearest, matches R4-R6 numerics) + bf16 lo
// (truncated; residual ~2^-17 rel, negligible). Packing via v_perm_b32.
__device__ __forceinline__ void split8(const float4& a, const float4& c,
                                       short8& h8, short8& l8) {
    union { short8 s; unsigned u[4]; } H, L;
    float vv[8] = {a.x, a.y, a.z, a.w, c.x, c.y, c.z, c.w};
#pragma unroll
    for (int p = 0; p < 4; p++) {
        const float v0 = vv[2*p], v1 = vv[2*p+1];
        const unsigned u0 = __float_as_uint(v0), u1 = __float_as_uint(v1);
        const unsigned r0 = u0 + 0x7fffu + ((u0 >> 16) & 1u);   // bf16 RN
        const unsigned r1 = u1 + 0x7fffu + ((u1 >> 16) & 1u);
        const float lo0 = v0 - __uint_as_float(r0 & 0xffff0000u);  // exact
        const float lo1 = v1 - __uint_as_float(r1 & 0xffff0000u);
        H.u[p] = __builtin_amdgcn_perm(r1, r0, 0x07060302u);       // hi16 pair
        L.u[p] = __builtin_amdgcn_perm(__float_as_uint(lo1),
                                       __float_as_uint(lo0), 0x07060302u);
    }
    h8 = H.s; l8 = L.s;
}

// Pre-split W (fp32 [64][4096]) -> ws bf16 hi/lo, fragment-linear:
// hi[((ck*2+nt)*64 + l)*8 + j] = bf16hi(W[nt*32+(l&31)][ck*16+(l>>5)*8+j]), lo at +WS_SHORTS
__global__ void wsplit_kernel(const float* __restrict__ W, short* __restrict__ wsp) {
    const int ck = blockIdx.x;          // 0..255
    const int t  = threadIdx.x;         // 0..127
    const int nt = t >> 6, l = t & 63;
    const int e  = nt * 32 + (l & 31);
    const int k  = ck * 16 + (l >> 5) * 8;
    const float* wp = W + (size_t)e * D_MODEL + k;
    float4 a = *(const float4*)wp, c = *(const float4*)(wp + 4);
    // exact RN split here (pre-kernel, cost irrelevant)
    union { short8 s; unsigned u[4]; } H, L;
    float vv[8] = {a.x, a.y, a.z, a.w, c.x, c.y, c.z, c.w};
#pragma unroll
    for (int p = 0; p < 4; p++) {
        const float v0 = vv[2*p], v1 = vv[2*p+1];
        const unsigned u0 = __float_as_uint(v0), u1 = __float_as_uint(v1);
        const unsigned r0 = u0 + 0x7fffu + ((u0 >> 16) & 1u);
        const unsigned r1 = u1 + 0x7fffu + ((u1 >> 16) & 1u);
        const float lo0 = v0 - __uint_as_float(r0 & 0xffff0000u);
        const float lo1 = v1 - __uint_as_float(r1 & 0xffff0000u);
        const unsigned q0 = __float_as_uint(lo0) + 0x7fffu + ((__float_as_uint(lo0) >> 16) & 1u);
        const unsigned q1 = __float_as_uint(lo1) + 0x7fffu + ((__float_as_uint(lo1) >> 16) & 1u);
        H.u[p] = __builtin_amdgcn_perm(r1, r0, 0x07060302u);
        L.u[p] = __builtin_amdgcn_perm(q1, q0, 0x07060302u);
    }
    const size_t off = ((size_t)(ck * 2 + nt) * 64 + l) * 8;
    *(short8*)(wsp + off)             = H.s;
    *(short8*)(wsp + WS_SHORTS + off) = L.s;
}

template<bool PRE>
__device__ __forceinline__ void ldw(const short* __restrict__ wsp,
                                    const float* __restrict__ W,
                                    int ck, int row, int kh, int lane,
                                    short8& b0h, short8& b0l,
                                    short8& b1h, short8& b1l) {
    if constexpr (PRE) {
        const size_t o0 = ((size_t)(ck * 2 + 0) * 64 + lane) * 8;
        const size_t o1 = ((size_t)(ck * 2 + 1) * 64 + lane) * 8;
        b0h = *(const short8*)(wsp + o0);
        b1h = *(const short8*)(wsp + o1);
        b0l = *(const short8*)(wsp + WS_SHORTS + o0);
        b1l = *(const short8*)(wsp + WS_SHORTS + o1);
    } else {
        const int k0 = ck * 16 + kh * 8;
        const float* w0 = W + (size_t)row * D_MODEL + k0;
        const float* w1 = W + (size_t)(32 + row) * D_MODEL + k0;
        split8(*(const float4*)w0, *(const float4*)(w0 + 4), b0h, b0l);
        split8(*(const float4*)w1, *(const float4*)(w1 + 4), b1h, b1l);
    }
}

template<bool PRE>
__global__ __launch_bounds__(512, 4) void router_kernel(
    const float* __restrict__ x, const float* __restrict__ W,
    const short* __restrict__ wsp, const float* __restrict__ b,
    float* __restrict__ out, int T)
{
    __shared__ short smem[16384];   // 32 KB: epilogue reduction slabs / logits

    const int tid  = threadIdx.x;
    const int wv   = __builtin_amdgcn_readfirstlane(tid >> 6); // 0..7 = K-region
    const int lane = tid & 63;
    const int tok0 = blockIdx.x * TPB;

    const int row = lane & 31;        // token-in-tile (A) / expert-in-group (B)
    const int kh  = lane >> 5;        // k-half of the 16-k step

    // this wave's x fragment stream: 32 B/lane/step, contiguous k
    const float* gx = x + (size_t)(tok0 + row) * D_MODEL + wv * KPW + kh * 8;

    f32x16 acc[2];
#pragma unroll
    for (int e = 0; e < 16; e++) { acc[0][e] = 0.f; acc[1][e] = 0.f; }

    // ---- modulo-scheduled pipeline: x 4-deep, W 2-deep, static slot indices
    float4 xA[4], xB[4];
    short8 b0h[2], b0l[2], b1h[2], b1l[2];

#define LDX(s_, u_) { const float* g_ = gx + (size_t)(s_) * 16;               \
        xA[u_] = *(const float4*)g_; xB[u_] = *(const float4*)(g_ + 4); }
#define LDW(s_, u_) ldw<PRE>(wsp, W, wv * WSTEPS + (s_), row, kh, lane,       \
                             b0h[u_], b0l[u_], b1h[u_], b1l[u_])
#define MF(A_, B_, n_) acc[n_] = __builtin_amdgcn_mfma_f32_32x32x16_bf16(     \
                             A_, B_, acc[n_], 0, 0, 0)
#define COMPUTE(u_) { short8 Ah_, Al_; split8(xA[u_], xB[u_], Ah_, Al_);      \
        MF(Ah_, b0h[(u_) & 1], 0); MF(Ah_, b0l[(u_) & 1], 0);                 \
        MF(Al_, b0h[(u_) & 1], 0); MF(Al_, b0l[(u_) & 1], 0);                 \
        MF(Ah_, b1h[(u_) & 1], 1); MF(Ah_, b1l[(u_) & 1], 1);                 \
        MF(Al_, b1h[(u_) & 1], 1); MF(Al_, b1l[(u_) & 1], 1); }
#define CL(v_) ((v_) < (WSTEPS - 1) ? (v_) : (WSTEPS - 1))   // clamp (dup load ok)

    // prologue: fill slots (interleaved so waits stay counted)
    LDX(0, 0); LDW(0, 0);
    LDX(1, 1); LDW(1, 1);
    LDX(2, 2);
    LDX(3, 3);

    for (int s = 0; s < WSTEPS; s += 4) {
        COMPUTE(0); LDW(CL(s + 2), 0); LDX(CL(s + 4), 0);
        COMPUTE(1); LDW(CL(s + 3), 1); LDX(CL(s + 5), 1);
        COMPUTE(2); LDW(CL(s + 4), 0); LDX(CL(s + 6), 2);
        COMPUTE(3); LDW(CL(s + 5), 1); LDX(CL(s + 7), 3);
    }
#undef LDX
#undef LDW
#undef MF
#undef COMPUTE
#undef CL

    // ---- single sync point: 3-round tree reduction over the 8 K-region waves
    float* red = (float*)smem;
    auto store_slab = [&](int slab) {
        float* sl = red + ((size_t)slab * 64 + lane) * 32;
#pragma unroll
        for (int q = 0; q < 8; q++) {   // quad q -> rotated slot (conflict-dodge)
            const int nt = q >> 2, rg = (q & 3) * 4;
            *(float4*)(sl + ((q + lane) & 7) * 4) =
                make_float4(acc[nt][rg], acc[nt][rg+1], acc[nt][rg+2], acc[nt][rg+3]);
        }
    };
    auto add_slab = [&](int slab) {
        const float* sl = red + ((size_t)slab * 64 + lane) * 32;
#pragma unroll
        for (int q = 0; q < 8; q++) {
            const int nt = q >> 2, rg = (q & 3) * 4;
            float4 v = *(const float4*)(sl + ((q + lane) & 7) * 4);
            acc[nt][rg] += v.x; acc[nt][rg+1] += v.y;
            acc[nt][rg+2] += v.z; acc[nt][rg+3] += v.w;
        }
    };
    __syncthreads();
    if (wv >= 4) store_slab(wv - 4);
    __syncthreads();
    if (wv < 4) add_slab(wv);
    __syncthreads();
    if (wv == 2 || wv == 3) store_slab(wv - 2);
    __syncthreads();
    if (wv < 2) add_slab(wv);
    __syncthreads();
    if (wv == 1) store_slab(0);
    __syncthreads();
    if (wv == 0) add_slab(0);
    __syncthreads();

    // ---- wave 0: logits(+bias) -> LDS [32 tok][68]
    float* lg = (float*)smem;
    if (wv == 0) {
        const int h = lane >> 5, c31 = lane & 31;
        const float bb0 = b[c31], bb1 = b[32 + c31];
#pragma unroll
        for (int nt = 0; nt < 2; nt++) {
#pragma unroll
            for (int e = 0; e < 16; e++) {
                const int r2 = (e & 3) + 8 * (e >> 2) + 4 * h;  // token in tile
                lg[r2 * 68 + nt * 32 + c31] = acc[nt][e] + (nt ? bb1 : bb0);
            }
        }
    }
    __syncthreads();

    // ---- top-2 + softmax + store (thread t = token)
    if (tid < TPB) {
        const float4* rowp = (const float4*)(lg + tid * 68);
        float v0 = -INFINITY, v1 = -INFINITY;
        int i0 = 0, i1 = 0;
#pragma unroll
        for (int q = 0; q < 16; q++) {
            float4 v4 = rowp[q];
            float vs[4] = {v4.x, v4.y, v4.z, v4.w};
#pragma unroll
            for (int j = 0; j < 4; j++) {
                const int e = q * 4 + j;
                const float v = vs[j];
                if (v > v0)      { v1 = v0; i1 = i0; v0 = v; i0 = e; }
                else if (v > v1) { v1 = v;  i1 = e; }
            }
        }
        const float e1 = expf(v1 - v0);     // v0 >= v1
        const float w0 = 1.f / (1.f + e1);
        const int tok = tok0 + tid;
        out[tok * 2 + 0] = w0;
        out[tok * 2 + 1] = e1 * w0;
        float* oi = out + (size_t)T * 2;    // indices chunk (float-cast)
        oi[tok * 2 + 0] = (float)i0;
        oi[tok * 2 + 1] = (float)i1;
    }
}

extern "C" void kernel_launch(void* const* d_in, const int* in_sizes, int n_in,
                              void* d_out, int out_size, void* d_ws, size_t ws_size,
                              hipStream_t stream) {
    const float* x = (const float*)d_in[0];
    const float* W = (const float*)d_in[1];
    const float* b = (const float*)d_in[2];
    float* out = (float*)d_out;
    short* wsp = (short*)d_ws;
    const int T = in_sizes[0] / D_MODEL;     // 16384 tokens
    const int grid = T / TPB;                // 512 blocks -> 2 per CU

    const bool pre = (ws_size >= (size_t)(2 * WS_SHORTS) * sizeof(short));  // 1 MB
    if (pre) {
        hipLaunchKernelGGL(wsplit_kernel, dim3(256), dim3(128), 0, stream, W, wsp);
        hipLaunchKernelGGL((router_kernel<true>), dim3(grid), dim3(512), 0, stream,
                           x, W, wsp, b, out, T);
    } else {
        hipLaunchKernelGGL((router_kernel<false>), dim3(grid), dim3(512), 0, stream,
                           x, W, wsp, b, out, T);
    }
}

// Round 8
// 69.730 us; speedup vs baseline: 1.9487x; 1.9487x over previous
//
#include <hip/hip_runtime.h>
#include <math.h>

#define D_MODEL 4096
#define NE 64
#define TPB 64                 // tokens per block
#define NSTEPS 64              // 4096 k / 64 k-per-step
#define BUFB 32768             // bytes per LDS buffer: 16K x | 8K Whi | 8K Wlo
#define WS_SHORTS (256 * 2 * 64 * 8)   // 262144 shorts per (hi|lo) region

typedef __attribute__((ext_vector_type(8))) short short8;
typedef __attribute__((ext_vector_type(16))) float f32x16;

__device__ __forceinline__ void gl_lds(const void* g, void* l) {
    __builtin_amdgcn_global_load_lds(
        (const __attribute__((address_space(1))) unsigned*)g,
        (__attribute__((address_space(3))) unsigned*)l, 16, 0, 0);
}

// Split 8 fp32 -> bf16 hi (RN) + bf16 lo (truncated residual), perm-packed.
__device__ __forceinline__ void split8(const float4& a, const float4& c,
                                       short8& h8, short8& l8) {
    union { short8 s; unsigned u[4]; } H, L;
    float vv[8] = {a.x, a.y, a.z, a.w, c.x, c.y, c.z, c.w};
#pragma unroll
    for (int p = 0; p < 4; p++) {
        const float v0 = vv[2*p], v1 = vv[2*p+1];
        const unsigned u0 = __float_as_uint(v0), u1 = __float_as_uint(v1);
        const unsigned r0 = u0 + 0x7fffu + ((u0 >> 16) & 1u);
        const unsigned r1 = u1 + 0x7fffu + ((u1 >> 16) & 1u);
        const float lo0 = v0 - __uint_as_float(r0 & 0xffff0000u);
        const float lo1 = v1 - __uint_as_float(r1 & 0xffff0000u);
        H.u[p] = __builtin_amdgcn_perm(r1, r0, 0x07060302u);
        L.u[p] = __builtin_amdgcn_perm(__float_as_uint(lo1),
                                       __float_as_uint(lo0), 0x07060302u);
    }
    h8 = H.s; l8 = L.s;
}

// Pre-split W -> ws bf16 hi/lo, fragment-linear:
// hi[((ck*2+nt)*64+l)*8+j] = bf16(W[nt*32+(l&31)][ck*16+(l>>5)*8+j]), lo at +WS_SHORTS
__global__ void wsplit_kernel(const float* __restrict__ W, short* __restrict__ wsp) {
    const int ck = blockIdx.x, t = threadIdx.x;
    const int nt = t >> 6, l = t & 63;
    const float* wp = W + (size_t)(nt * 32 + (l & 31)) * D_MODEL + ck * 16 + (l >> 5) * 8;
    float4 a = *(const float4*)wp, c = *(const float4*)(wp + 4);
    union { short8 s; unsigned u[4]; } H, L;
    float vv[8] = {a.x, a.y, a.z, a.w, c.x, c.y, c.z, c.w};
#pragma unroll
    for (int p = 0; p < 4; p++) {
        const float v0 = vv[2*p], v1 = vv[2*p+1];
        const unsigned u0 = __float_as_uint(v0), u1 = __float_as_uint(v1);
        const unsigned r0 = u0 + 0x7fffu + ((u0 >> 16) & 1u);
        const unsigned r1 = u1 + 0x7fffu + ((u1 >> 16) & 1u);
        const float lo0 = v0 - __uint_as_float(r0 & 0xffff0000u);
        const float lo1 = v1 - __uint_as_float(r1 & 0xffff0000u);
        const unsigned q0 = __float_as_uint(lo0) + 0x7fffu + ((__float_as_uint(lo0) >> 16) & 1u);
        const unsigned q1 = __float_as_uint(lo1) + 0x7fffu + ((__float_as_uint(lo1) >> 16) & 1u);
        H.u[p] = __builtin_amdgcn_perm(r1, r0, 0x07060302u);
        L.u[p] = __builtin_amdgcn_perm(q1, q0, 0x07060302u);
    }
    const size_t off = ((size_t)(ck * 2 + nt) * 64 + l) * 8;
    *(short8*)(wsp + off)             = H.s;
    *(short8*)(wsp + WS_SHORTS + off) = L.s;
}

#define MF(A_, B_, n_) acc[n_] = __builtin_amdgcn_mfma_f32_32x32x16_bf16( \
                             A_, B_, acc[n_], 0, 0, 0)

// T3/T4: global_load_lds staging, counted vmcnt(8), raw barrier (never drain-0).
__global__ __launch_bounds__(512) void router_pipe(
    const float* __restrict__ x, const short* __restrict__ wsp,
    const float* __restrict__ b, float* __restrict__ out, int T)
{
    __shared__ char smem[4 * BUFB];   // 128 KB, 4 buffers

    const int tid  = threadIdx.x;
    const int wv   = tid >> 6, lane = tid & 63;
    const int mt   = wv & 1;          // token half-tile
    const int kq   = wv >> 1;         // k-quarter of each 64-k step
    const int tok0 = blockIdx.x * TPB;

    // ---- staging sources (per-lane). x LDS layout [tok][chunk^ (tok&15)][16B]
    const int tokA = tid >> 4, clA = tid & 15;   // op1: tokens 0..31
    const int tokB = 32 + tokA;                  // op2: tokens 32..63
    const float* gx1 = x + (size_t)(tok0 + tokA) * D_MODEL + ((clA ^ (tokA & 15)) * 4);
    const float* gx2 = x + (size_t)(tok0 + tokB) * D_MODEL + ((clA ^ (tokB & 15)) * 4);
    const char* whi = (const char*)wsp + (size_t)tid * 16;
    const char* wlo = (const char*)(wsp + WS_SHORTS) + (size_t)tid * 16;

#define STAGE(sc_, bi_) do {                                                  \
        char* db_ = smem + (bi_) * BUFB + wv * 1024;                          \
        gl_lds(gx1 + (size_t)(sc_) * 64, db_);                                \
        gl_lds(gx2 + (size_t)(sc_) * 64, db_ + 8192);                         \
        gl_lds(whi + (size_t)(sc_) * 8192, db_ + 16384);                      \
        gl_lds(wlo + (size_t)(sc_) * 8192, db_ + 24576);                      \
    } while (0)

    f32x16 acc[2];
#pragma unroll
    for (int e = 0; e < 16; e++) { acc[0][e] = 0.f; acc[1][e] = 0.f; }

    // fragment read offsets
    const int row = mt * 32 + (lane & 31);       // token row in tile
    const int c0  = kq * 4 + (lane >> 5) * 2;    // 16B chunk of this lane's k
    const int xo1 = row * 256 + ((c0     ^ (row & 15)) * 16);
    const int xo2 = row * 256 + (((c0+1) ^ (row & 15)) * 16);
    const int wo0 = 16384 + ((kq * 2 + 0) * 64 + lane) * 16;
    const int wo1 = 16384 + ((kq * 2 + 1) * 64 + lane) * 16;

    STAGE(0, 0);
    STAGE(1, 1);

    for (int s = 0; s < NSTEPS; ++s) {
        const int sc = (s + 2 < NSTEPS) ? s + 2 : NSTEPS - 1;  // tail: dup-stage
        STAGE(sc, (s + 2) & 3);
        asm volatile("s_waitcnt vmcnt(8)" ::: "memory");   // own step-s ops done
        __builtin_amdgcn_s_barrier();                      // all waves' step-s done
        __builtin_amdgcn_sched_barrier(0);
        const char* buf = smem + (s & 3) * BUFB;
        float4 xa = *(const float4*)(buf + xo1);
        float4 xb = *(const float4*)(buf + xo2);
        short8 b0h = *(const short8*)(buf + wo0);
        short8 b1h = *(const short8*)(buf + wo1);
        short8 b0l = *(const short8*)(buf + wo0 + 8192);
        short8 b1l = *(const short8*)(buf + wo1 + 8192);
        short8 Ah, Al;
        split8(xa, xb, Ah, Al);
        MF(Ah, b0h, 0); MF(Ah, b0l, 0); MF(Al, b0h, 0); MF(Al, b0l, 0);
        MF(Ah, b1h, 1); MF(Ah, b1l, 1); MF(Al, b1h, 1); MF(Al, b1l, 1);
    }
#undef STAGE

    asm volatile("s_waitcnt vmcnt(0)" ::: "memory");       // drain dup-stages
    __builtin_amdgcn_s_barrier();
    __builtin_amdgcn_sched_barrier(0);

    // ---- reduce 4 k-quarters per mt (2 rounds, rotate-swizzled slabs)
    float* red = (float*)smem;
    auto store_slab = [&](int slab) {
        float* sl = red + ((size_t)slab * 64 + lane) * 32;
#pragma unroll
        for (int q = 0; q < 8; q++) {
            const int nt = q >> 2, rg = (q & 3) * 4;
            *(float4*)(sl + ((q + lane) & 7) * 4) =
                make_float4(acc[nt][rg], acc[nt][rg+1], acc[nt][rg+2], acc[nt][rg+3]);
        }
    };
    auto add_slab = [&](int slab) {
        const float* sl = red + ((size_t)slab * 64 + lane) * 32;
#pragma unroll
        for (int q = 0; q < 8; q++) {
            const int nt = q >> 2, rg = (q & 3) * 4;
            float4 v = *(const float4*)(sl + ((q + lane) & 7) * 4);
            acc[nt][rg] += v.x; acc[nt][rg+1] += v.y;
            acc[nt][rg+2] += v.z; acc[nt][rg+3] += v.w;
        }
    };
    if (kq >= 2) store_slab(mt * 2 + (kq - 2));
    __syncthreads();
    if (kq < 2) add_slab(mt * 2 + kq);
    __syncthreads();
    if (kq == 1) store_slab(mt);
    __syncthreads();
    if (kq == 0) add_slab(mt);
    __syncthreads();

    // ---- logits(+bias) -> LDS [64 tok][68]
    float* lg = (float*)(smem + 49152);
    if (kq == 0) {
        const int h = lane >> 5, c31 = lane & 31;
        const float bb0 = b[c31], bb1 = b[32 + c31];
#pragma unroll
        for (int nt = 0; nt < 2; nt++) {
#pragma unroll
            for (int e = 0; e < 16; e++) {
                const int r2 = (e & 3) + 8 * (e >> 2) + 4 * h;
                lg[(mt * 32 + r2) * 68 + nt * 32 + c31] = acc[nt][e] + (nt ? bb1 : bb0);
            }
        }
    }
    __syncthreads();

    // ---- top-2 + softmax + store (thread t = token)
    if (tid < TPB) {
        const float4* rowp = (const float4*)(lg + tid * 68);
        float v0 = -INFINITY, v1 = -INFINITY;
        int i0 = 0, i1 = 0;
#pragma unroll
        for (int q = 0; q < 16; q++) {
            float4 v4 = rowp[q];
            float vs[4] = {v4.x, v4.y, v4.z, v4.w};
#pragma unroll
            for (int j = 0; j < 4; j++) {
                const int e = q * 4 + j;
                const float v = vs[j];
                if (v > v0)      { v1 = v0; i1 = i0; v0 = v; i0 = e; }
                else if (v > v1) { v1 = v;  i1 = e; }
            }
        }
        const float e1 = expf(v1 - v0);     // v0 >= v1
        const float w0 = 1.f / (1.f + e1);
        const int tok = tok0 + tid;
        out[tok * 2 + 0] = w0;
        out[tok * 2 + 1] = e1 * w0;
        float* oi = out + (size_t)T * 2;    // indices chunk (float-cast)
        oi[tok * 2 + 0] = (float)i0;
        oi[tok * 2 + 1] = (float)i1;
    }
}

// Fallback (ws too small): R6 barrier-free kernel with in-loop W split (proven).
__global__ __launch_bounds__(512, 4) void router_fb(
    const float* __restrict__ x, const float* __restrict__ W,
    const float* __restrict__ b, float* __restrict__ out, int T)
{
    __shared__ short smem[16384];
    const int tid = threadIdx.x;
    const int wv = tid >> 6, lane = tid & 63;
    const int tok0 = blockIdx.x * 32;
    const int row = lane & 31, kh = lane >> 5;
    const float* gx = x + (size_t)(tok0 + row) * D_MODEL + wv * 512 + kh * 8;
    f32x16 acc[2];
#pragma unroll
    for (int e = 0; e < 16; e++) { acc[0][e] = 0.f; acc[1][e] = 0.f; }
    for (int s = 0; s < 32; s++) {
        const float* g = gx + (size_t)s * 16;
        float4 xa = *(const float4*)g, xb = *(const float4*)(g + 4);
        const int k0 = wv * 512 + s * 16 + kh * 8;
        const float* w0 = W + (size_t)row * D_MODEL + k0;
        const float* w1 = W + (size_t)(32 + row) * D_MODEL + k0;
        short8 Ah, Al, B0h, B0l, B1h, B1l;
        split8(xa, xb, Ah, Al);
        split8(*(const float4*)w0, *(const float4*)(w0 + 4), B0h, B0l);
        split8(*(const float4*)w1, *(const float4*)(w1 + 4), B1h, B1l);
        MF(Ah, B0h, 0); MF(Ah, B0l, 0); MF(Al, B0h, 0); MF(Al, B0l, 0);
        MF(Ah, B1h, 1); MF(Ah, B1l, 1); MF(Al, B1h, 1); MF(Al, B1l, 1);
    }
    float* red = (float*)smem;
    auto store_slab = [&](int slab) {
        float* sl = red + ((size_t)slab * 64 + lane) * 32;
#pragma unroll
        for (int q = 0; q < 8; q++) {
            const int nt = q >> 2, rg = (q & 3) * 4;
            *(float4*)(sl + ((q + lane) & 7) * 4) =
                make_float4(acc[nt][rg], acc[nt][rg+1], acc[nt][rg+2], acc[nt][rg+3]);
        }
    };
    auto add_slab = [&](int slab) {
        const float* sl = red + ((size_t)slab * 64 + lane) * 32;
#pragma unroll
        for (int q = 0; q < 8; q++) {
            const int nt = q >> 2, rg = (q & 3) * 4;
            float4 v = *(const float4*)(sl + ((q + lane) & 7) * 4);
            acc[nt][rg] += v.x; acc[nt][rg+1] += v.y;
            acc[nt][rg+2] += v.z; acc[nt][rg+3] += v.w;
        }
    };
    __syncthreads();
    if (wv >= 4) store_slab(wv - 4);
    __syncthreads();
    if (wv < 4) add_slab(wv);
    __syncthreads();
    if (wv == 2 || wv == 3) store_slab(wv - 2);
    __syncthreads();
    if (wv < 2) add_slab(wv);
    __syncthreads();
    if (wv == 1) store_slab(0);
    __syncthreads();
    if (wv == 0) add_slab(0);
    __syncthreads();
    float* lg = (float*)smem;
    if (wv == 0) {
        const int h = lane >> 5, c31 = lane & 31;
        const float bb0 = b[c31], bb1 = b[32 + c31];
#pragma unroll
        for (int nt = 0; nt < 2; nt++)
#pragma unroll
            for (int e = 0; e < 16; e++) {
                const int r2 = (e & 3) + 8 * (e >> 2) + 4 * h;
                lg[r2 * 68 + nt * 32 + c31] = acc[nt][e] + (nt ? bb1 : bb0);
            }
    }
    __syncthreads();
    if (tid < 32) {
        const float4* rowp = (const float4*)(lg + tid * 68);
        float v0 = -INFINITY, v1 = -INFINITY;
        int i0 = 0, i1 = 0;
#pragma unroll
        for (int q = 0; q < 16; q++) {
            float4 v4 = rowp[q];
            float vs[4] = {v4.x, v4.y, v4.z, v4.w};
#pragma unroll
            for (int j = 0; j < 4; j++) {
                const float v = vs[j];
                if (v > v0)      { v1 = v0; i1 = i0; v0 = v; i0 = q*4+j; }
                else if (v > v1) { v1 = v;  i1 = q*4+j; }
            }
        }
        const float e1 = expf(v1 - v0);
        const float w0 = 1.f / (1.f + e1);
        const int tok = tok0 + tid;
        out[tok * 2 + 0] = w0;
        out[tok * 2 + 1] = e1 * w0;
        float* oi = out + (size_t)T * 2;
        oi[tok * 2 + 0] = (float)i0;
        oi[tok * 2 + 1] = (float)i1;
    }
}

extern "C" void kernel_launch(void* const* d_in, const int* in_sizes, int n_in,
                              void* d_out, int out_size, void* d_ws, size_t ws_size,
                              hipStream_t stream) {
    const float* x = (const float*)d_in[0];
    const float* W = (const float*)d_in[1];
    const float* b = (const float*)d_in[2];
    float* out = (float*)d_out;
    short* wsp = (short*)d_ws;
    const int T = in_sizes[0] / D_MODEL;     // 16384 tokens

    const bool pre = (ws_size >= (size_t)(2 * WS_SHORTS) * sizeof(short));  // 1 MB
    if (pre) {
        hipLaunchKernelGGL(wsplit_kernel, dim3(256), dim3(128), 0, stream, W, wsp);
        hipLaunchKernelGGL(router_pipe, dim3(T / TPB), dim3(512), 0, stream,
                           x, wsp, b, out, T);
    } else {
        hipLaunchKernelGGL(router_fb, dim3(T / 32), dim3(512), 0, stream,
                           x, W, b, out, T);
    }
}

// Round 9
// 67.842 us; speedup vs baseline: 2.0029x; 1.0278x over previous
//
#include <hip/hip_runtime.h>
#include <math.h>

#define D_MODEL 4096
#define NE 64
#define TPB 64                 // tokens per block
#define NSTEPS 64              // 4096 k / 64 k-per-step
#define BUFB 32768             // bytes per LDS buffer: 16K x | 8K Whi | 8K Wlo
#define NBUF 5                 // 160 KB LDS, stage distance = NBUF-2 = 3
#define WS_SHORTS (256 * 2 * 64 * 8)   // 262144 shorts per (hi|lo) region

typedef __attribute__((ext_vector_type(8))) short short8;
typedef __attribute__((ext_vector_type(16))) float f32x16;

__device__ __forceinline__ void gl_lds(const void* g, void* l) {
    __builtin_amdgcn_global_load_lds(
        (const __attribute__((address_space(1))) unsigned*)g,
        (__attribute__((address_space(3))) unsigned*)l, 16, 0, 0);
}

// Split 8 fp32 -> bf16 hi (RN) + bf16 lo (truncated residual), perm-packed.
__device__ __forceinline__ void split8(const float4& a, const float4& c,
                                       short8& h8, short8& l8) {
    union { short8 s; unsigned u[4]; } H, L;
    float vv[8] = {a.x, a.y, a.z, a.w, c.x, c.y, c.z, c.w};
#pragma unroll
    for (int p = 0; p < 4; p++) {
        const float v0 = vv[2*p], v1 = vv[2*p+1];
        const unsigned u0 = __float_as_uint(v0), u1 = __float_as_uint(v1);
        const unsigned r0 = u0 + 0x7fffu + ((u0 >> 16) & 1u);
        const unsigned r1 = u1 + 0x7fffu + ((u1 >> 16) & 1u);
        const float lo0 = v0 - __uint_as_float(r0 & 0xffff0000u);
        const float lo1 = v1 - __uint_as_float(r1 & 0xffff0000u);
        H.u[p] = __builtin_amdgcn_perm(r1, r0, 0x07060302u);
        L.u[p] = __builtin_amdgcn_perm(__float_as_uint(lo1),
                                       __float_as_uint(lo0), 0x07060302u);
    }
    h8 = H.s; l8 = L.s;
}

// Pre-split W -> ws bf16 hi/lo, fragment-linear:
// hi[((ck*2+nt)*64+l)*8+j] = bf16(W[nt*32+(l&31)][ck*16+(l>>5)*8+j]), lo at +WS_SHORTS
__global__ void wsplit_kernel(const float* __restrict__ W, short* __restrict__ wsp) {
    const int ck = blockIdx.x, t = threadIdx.x;
    const int nt = t >> 6, l = t & 63;
    const float* wp = W + (size_t)(nt * 32 + (l & 31)) * D_MODEL + ck * 16 + (l >> 5) * 8;
    float4 a = *(const float4*)wp, c = *(const float4*)(wp + 4);
    union { short8 s; unsigned u[4]; } H, L;
    float vv[8] = {a.x, a.y, a.z, a.w, c.x, c.y, c.z, c.w};
#pragma unroll
    for (int p = 0; p < 4; p++) {
        const float v0 = vv[2*p], v1 = vv[2*p+1];
        const unsigned u0 = __float_as_uint(v0), u1 = __float_as_uint(v1);
        const unsigned r0 = u0 + 0x7fffu + ((u0 >> 16) & 1u);
        const unsigned r1 = u1 + 0x7fffu + ((u1 >> 16) & 1u);
        const float lo0 = v0 - __uint_as_float(r0 & 0xffff0000u);
        const float lo1 = v1 - __uint_as_float(r1 & 0xffff0000u);
        const unsigned q0 = __float_as_uint(lo0) + 0x7fffu + ((__float_as_uint(lo0) >> 16) & 1u);
        const unsigned q1 = __float_as_uint(lo1) + 0x7fffu + ((__float_as_uint(lo1) >> 16) & 1u);
        H.u[p] = __builtin_amdgcn_perm(r1, r0, 0x07060302u);
        L.u[p] = __builtin_amdgcn_perm(q1, q0, 0x07060302u);
    }
    const size_t off = ((size_t)(ck * 2 + nt) * 64 + l) * 8;
    *(short8*)(wsp + off)             = H.s;
    *(short8*)(wsp + WS_SHORTS + off) = L.s;
}

#define MF(A_, B_, n_) acc[n_] = __builtin_amdgcn_mfma_f32_32x32x16_bf16( \
                             A_, B_, acc[n_], 0, 0, 0)

// T3/T4: global_load_lds staging, 5 buffers, stage s+3, counted vmcnt.
__global__ __launch_bounds__(512) void router_pipe(
    const float* __restrict__ x, const short* __restrict__ wsp,
    const float* __restrict__ b, float* __restrict__ out, int T)
{
    __shared__ char smem[NBUF * BUFB];   // 160 KB

    const int tid  = threadIdx.x;
    const int wv   = tid >> 6, lane = tid & 63;
    const int mt   = wv & 1;          // token half-tile
    const int kq   = wv >> 1;         // k-quarter of each 64-k step
    const int tok0 = blockIdx.x * TPB;

    // ---- staging sources (per-lane). x LDS layout [tok][chunk^(tok&15)][16B]
    const int tokA = tid >> 4, clA = tid & 15;   // op1: tokens 0..31
    const int tokB = 32 + tokA;                  // op2: tokens 32..63
    const float* gx1 = x + (size_t)(tok0 + tokA) * D_MODEL + ((clA ^ (tokA & 15)) * 4);
    const float* gx2 = x + (size_t)(tok0 + tokB) * D_MODEL + ((clA ^ (tokB & 15)) * 4);
    const char* whi = (const char*)wsp + (size_t)tid * 16;
    const char* wlo = (const char*)(wsp + WS_SHORTS) + (size_t)tid * 16;

    auto stage = [&](int sc, int bi) {
        char* db = smem + bi * BUFB + wv * 1024;
        gl_lds(gx1 + (size_t)sc * 64, db);
        gl_lds(gx2 + (size_t)sc * 64, db + 8192);
        gl_lds(whi + (size_t)sc * 8192, db + 16384);
        gl_lds(wlo + (size_t)sc * 8192, db + 24576);
    };

    f32x16 acc[2];
#pragma unroll
    for (int e = 0; e < 16; e++) { acc[0][e] = 0.f; acc[1][e] = 0.f; }

    // fragment read offsets
    const int row = mt * 32 + (lane & 31);       // token row in tile
    const int c0  = kq * 4 + (lane >> 5) * 2;    // 16B chunk of this lane's k
    const int xo1 = row * 256 + ((c0     ^ (row & 15)) * 16);
    const int xo2 = row * 256 + (((c0+1) ^ (row & 15)) * 16);
    const int wo0 = 16384 + ((kq * 2 + 0) * 64 + lane) * 16;
    const int wo1 = 16384 + ((kq * 2 + 1) * 64 + lane) * 16;

    auto compute = [&](int bi) {
        const char* buf = smem + bi * BUFB;
        float4 xa = *(const float4*)(buf + xo1);
        float4 xb = *(const float4*)(buf + xo2);
        short8 b0h = *(const short8*)(buf + wo0);
        short8 b1h = *(const short8*)(buf + wo1);
        short8 b0l = *(const short8*)(buf + wo0 + 8192);
        short8 b1l = *(const short8*)(buf + wo1 + 8192);
        short8 Ah, Al;
        split8(xa, xb, Ah, Al);
        MF(Ah, b0h, 0); MF(Ah, b0l, 0); MF(Al, b0h, 0); MF(Al, b0l, 0);
        MF(Ah, b1h, 1); MF(Ah, b1l, 1); MF(Al, b1h, 1); MF(Al, b1l, 1);
    };

    // prologue: fill 3 buffers
    stage(0, 0); stage(1, 1); stage(2, 2);

    int bs = 3, bc = 0;
    for (int s = 0; s < NSTEPS - 3; ++s) {
        stage(s + 3, bs);
        // outstanding: steps s..s+3 = 16 ops; wait for step-s's 4
        asm volatile("s_waitcnt vmcnt(12)" ::: "memory");
        __builtin_amdgcn_s_barrier();
        __builtin_amdgcn_sched_barrier(0);
        compute(bc);
        if (++bs == NBUF) bs = 0;
        if (++bc == NBUF) bc = 0;
    }
    // tail: 3 steps, counted drains (no dup-stages)
    asm volatile("s_waitcnt vmcnt(8)" ::: "memory");
    __builtin_amdgcn_s_barrier();
    __builtin_amdgcn_sched_barrier(0);
    compute(bc); if (++bc == NBUF) bc = 0;
    asm volatile("s_waitcnt vmcnt(4)" ::: "memory");
    __builtin_amdgcn_s_barrier();
    __builtin_amdgcn_sched_barrier(0);
    compute(bc); if (++bc == NBUF) bc = 0;
    asm volatile("s_waitcnt vmcnt(0)" ::: "memory");
    __builtin_amdgcn_s_barrier();
    __builtin_amdgcn_sched_barrier(0);
    compute(bc);

    __syncthreads();

    // ---- reduce 4 k-quarters per mt (2 rounds, rotate-swizzled slabs)
    float* red = (float*)smem;
    auto store_slab = [&](int slab) {
        float* sl = red + ((size_t)slab * 64 + lane) * 32;
#pragma unroll
        for (int q = 0; q < 8; q++) {
            const int nt = q >> 2, rg = (q & 3) * 4;
            *(float4*)(sl + ((q + lane) & 7) * 4) =
                make_float4(acc[nt][rg], acc[nt][rg+1], acc[nt][rg+2], acc[nt][rg+3]);
        }
    };
    auto add_slab = [&](int slab) {
        const float* sl = red + ((size_t)slab * 64 + lane) * 32;
#pragma unroll
        for (int q = 0; q < 8; q++) {
            const int nt = q >> 2, rg = (q & 3) * 4;
            float4 v = *(const float4*)(sl + ((q + lane) & 7) * 4);
            acc[nt][rg] += v.x; acc[nt][rg+1] += v.y;
            acc[nt][rg+2] += v.z; acc[nt][rg+3] += v.w;
        }
    };
    if (kq >= 2) store_slab(mt * 2 + (kq - 2));
    __syncthreads();
    if (kq < 2) add_slab(mt * 2 + kq);
    __syncthreads();
    if (kq == 1) store_slab(mt);
    __syncthreads();
    if (kq == 0) add_slab(mt);
    __syncthreads();

    // ---- logits(+bias) -> LDS [64 tok][68]
    float* lg = (float*)(smem + 49152);
    if (kq == 0) {
        const int h = lane >> 5, c31 = lane & 31;
        const float bb0 = b[c31], bb1 = b[32 + c31];
#pragma unroll
        for (int nt = 0; nt < 2; nt++) {
#pragma unroll
            for (int e = 0; e < 16; e++) {
                const int r2 = (e & 3) + 8 * (e >> 2) + 4 * h;
                lg[(mt * 32 + r2) * 68 + nt * 32 + c31] = acc[nt][e] + (nt ? bb1 : bb0);
            }
        }
    }
    __syncthreads();

    // ---- top-2 + softmax + store (thread t = token)
    if (tid < TPB) {
        const float4* rowp = (const float4*)(lg + tid * 68);
        float v0 = -INFINITY, v1 = -INFINITY;
        int i0 = 0, i1 = 0;
#pragma unroll
        for (int q = 0; q < 16; q++) {
            float4 v4 = rowp[q];
            float vs[4] = {v4.x, v4.y, v4.z, v4.w};
#pragma unroll
            for (int j = 0; j < 4; j++) {
                const int e = q * 4 + j;
                const float v = vs[j];
                if (v > v0)      { v1 = v0; i1 = i0; v0 = v; i0 = e; }
                else if (v > v1) { v1 = v;  i1 = e; }
            }
        }
        const float e1 = expf(v1 - v0);     // v0 >= v1
        const float w0 = 1.f / (1.f + e1);
        const int tok = tok0 + tid;
        out[tok * 2 + 0] = w0;
        out[tok * 2 + 1] = e1 * w0;
        float* oi = out + (size_t)T * 2;    // indices chunk (float-cast)
        oi[tok * 2 + 0] = (float)i0;
        oi[tok * 2 + 1] = (float)i1;
    }
}

// Fallback (ws too small): R6 barrier-free kernel with in-loop W split.
__global__ __launch_bounds__(512, 4) void router_fb(
    const float* __restrict__ x, const float* __restrict__ W,
    const float* __restrict__ b, float* __restrict__ out, int T)
{
    __shared__ short smem[16384];
    const int tid = threadIdx.x;
    const int wv = tid >> 6, lane = tid & 63;
    const int tok0 = blockIdx.x * 32;
    const int row = lane & 31, kh = lane >> 5;
    const float* gx = x + (size_t)(tok0 + row) * D_MODEL + wv * 512 + kh * 8;
    f32x16 acc[2];
#pragma unroll
    for (int e = 0; e < 16; e++) { acc[0][e] = 0.f; acc[1][e] = 0.f; }
    for (int s = 0; s < 32; s++) {
        const float* g = gx + (size_t)s * 16;
        float4 xa = *(const float4*)g, xb = *(const float4*)(g + 4);
        const int k0 = wv * 512 + s * 16 + kh * 8;
        const float* w0 = W + (size_t)row * D_MODEL + k0;
        const float* w1 = W + (size_t)(32 + row) * D_MODEL + k0;
        short8 Ah, Al, B0h, B0l, B1h, B1l;
        split8(xa, xb, Ah, Al);
        split8(*(const float4*)w0, *(const float4*)(w0 + 4), B0h, B0l);
        split8(*(const float4*)w1, *(const float4*)(w1 + 4), B1h, B1l);
        MF(Ah, B0h, 0); MF(Ah, B0l, 0); MF(Al, B0h, 0); MF(Al, B0l, 0);
        MF(Ah, B1h, 1); MF(Ah, B1l, 1); MF(Al, B1h, 1); MF(Al, B1l, 1);
    }
    float* red = (float*)smem;
    auto store_slab = [&](int slab) {
        float* sl = red + ((size_t)slab * 64 + lane) * 32;
#pragma unroll
        for (int q = 0; q < 8; q++) {
            const int nt = q >> 2, rg = (q & 3) * 4;
            *(float4*)(sl + ((q + lane) & 7) * 4) =
                make_float4(acc[nt][rg], acc[nt][rg+1], acc[nt][rg+2], acc[nt][rg+3]);
        }
    };
    auto add_slab = [&](int slab) {
        const float* sl = red + ((size_t)slab * 64 + lane) * 32;
#pragma unroll
        for (int q = 0; q < 8; q++) {
            const int nt = q >> 2, rg = (q & 3) * 4;
            float4 v = *(const float4*)(sl + ((q + lane) & 7) * 4);
            acc[nt][rg] += v.x; acc[nt][rg+1] += v.y;
            acc[nt][rg+2] += v.z; acc[nt][rg+3] += v.w;
        }
    };
    __syncthreads();
    if (wv >= 4) store_slab(wv - 4);
    __syncthreads();
    if (wv < 4) add_slab(wv);
    __syncthreads();
    if (wv == 2 || wv == 3) store_slab(wv - 2);
    __syncthreads();
    if (wv < 2) add_slab(wv);
    __syncthreads();
    if (wv == 1) store_slab(0);
    __syncthreads();
    if (wv == 0) add_slab(0);
    __syncthreads();
    float* lg = (float*)smem;
    if (wv == 0) {
        const int h = lane >> 5, c31 = lane & 31;
        const float bb0 = b[c31], bb1 = b[32 + c31];
#pragma unroll
        for (int nt = 0; nt < 2; nt++)
#pragma unroll
            for (int e = 0; e < 16; e++) {
                const int r2 = (e & 3) + 8 * (e >> 2) + 4 * h;
                lg[r2 * 68 + nt * 32 + c31] = acc[nt][e] + (nt ? bb1 : bb0);
            }
    }
    __syncthreads();
    if (tid < 32) {
        const float4* rowp = (const float4*)(lg + tid * 68);
        float v0 = -INFINITY, v1 = -INFINITY;
        int i0 = 0, i1 = 0;
#pragma unroll
        for (int q = 0; q < 16; q++) {
            float4 v4 = rowp[q];
            float vs[4] = {v4.x, v4.y, v4.z, v4.w};
#pragma unroll
            for (int j = 0; j < 4; j++) {
                const float v = vs[j];
                if (v > v0)      { v1 = v0; i1 = i0; v0 = v; i0 = q*4+j; }
                else if (v > v1) { v1 = v;  i1 = q*4+j; }
            }
        }
        const float e1 = expf(v1 - v0);
        const float w0 = 1.f / (1.f + e1);
        const int tok = tok0 + tid;
        out[tok * 2 + 0] = w0;
        out[tok * 2 + 1] = e1 * w0;
        float* oi = out + (size_t)T * 2;
        oi[tok * 2 + 0] = (float)i0;
        oi[tok * 2 + 1] = (float)i1;
    }
}

extern "C" void kernel_launch(void* const* d_in, const int* in_sizes, int n_in,
                              void* d_out, int out_size, void* d_ws, size_t ws_size,
                              hipStream_t stream) {
    const float* x = (const float*)d_in[0];
    const float* W = (const float*)d_in[1];
    const float* b = (const float*)d_in[2];
    float* out = (float*)d_out;
    short* wsp = (short*)d_ws;
    const int T = in_sizes[0] / D_MODEL;     // 16384 tokens

    const bool pre = (ws_size >= (size_t)(2 * WS_SHORTS) * sizeof(short));  // 1 MB
    if (pre) {
        hipLaunchKernelGGL(wsplit_kernel, dim3(256), dim3(128), 0, stream, W, wsp);
        hipLaunchKernelGGL(router_pipe, dim3(T / TPB), dim3(512), 0, stream,
                           x, wsp, b, out, T);
    } else {
        hipLaunchKernelGGL(router_fb, dim3(T / 32), dim3(512), 0, stream,
                           x, W, b, out, T);
    }
}